// Round 5
// baseline (3769.509 us; speedup 1.0000x reference)
//
#include <hip/hip_runtime.h>
#include <math.h>

#define B_ 512
#define N_ 20
#define H_ 450
#define L_ 56
#define V_ 780
#define T_ 38
#define NNODES (B_*N_)        // 10240
#define NEDGES (B_*2*(N_-1))  // 19456
#define NPROWS ((T_+1)*B_)    // 19968
#define MAXP 8
#define MAXD 8
#define KP 928                // padded K for scan GEMMs (900 -> 928 = 29*32)
#define SROW 936              // LDS row stride (shorts): 1872B -> 2-way bank alias (free)

typedef __attribute__((ext_vector_type(8))) short bf16x8;
typedef __attribute__((ext_vector_type(4))) float f32x4;

__device__ __forceinline__ float sigmoidf_(float v){ return 1.0f/(1.0f+expf(-v)); }

// f32 -> bf16 (RNE)
__device__ __forceinline__ unsigned short f2b(float x){
  unsigned int u = __float_as_uint(x);
  unsigned int r = (u + 0x7fffu + ((u >> 16) & 1u)) >> 16;
  return (unsigned short)r;
}
__device__ __forceinline__ float b2f(unsigned short v){
  return __uint_as_float((unsigned int)v << 16);
}
__device__ __forceinline__ unsigned int pack2(float lo, float hi){
  return (unsigned int)f2b(lo) | ((unsigned int)f2b(hi) << 16);
}

// ---------------------------------------------------------------------------
// x[i][:] = emb[wid[i]][:]  (f32), one wave per row, float2
__global__ __launch_bounds__(256) void k_gather_x(const float* __restrict__ emb,
    const int* __restrict__ wid, float* __restrict__ x){
  int w = blockIdx.x*4 + (threadIdx.x>>6), lane = threadIdx.x & 63;
  if (w >= NNODES) return;
  const float2* src = (const float2*)(emb + (size_t)wid[w]*H_);
  float2* dst = (float2*)(x + (size_t)w*H_);
  for (int j2 = lane; j2 < 225; j2 += 64) dst[j2] = src[j2];
}

// Transpose+convert weight to K-major bf16 with zero padding.
__global__ void k_wt(const float* __restrict__ W1, const float* __restrict__ W2,
                     int Ksplit, int Kact, int Nact, unsigned short* __restrict__ dst, int Kpad){
  int c = blockIdx.x;
  unsigned short* drow = dst + (size_t)c*Kpad;
  for (int k = threadIdx.x; k < Kpad; k += blockDim.x){
    float v = 0.f;
    if (c < Nact && k < Kact)
      v = (k < Ksplit) ? W1[(size_t)k*Nact + c] : W2[(size_t)(k-Ksplit)*Nact + c];
    drow[k] = f2b(v);
  }
}

// ---------------------------------------------------------------------------
// Fused 38-step scan. One block owns 16 trees for all steps; no cross-block deps
// (m/rm rows are per-tree; weights read-only). 1024 threads = 16 waves; wave wv
// computes cols [32wv, 32wv+32) of the 512-padded output.
__global__ __launch_bounds__(1024) void k_scan_all(
    const float* __restrict__ x,
    const unsigned short* __restrict__ WzT, const unsigned short* __restrict__ WhT,
    const unsigned short* __restrict__ WrUrT,
    const float* __restrict__ bz, const float* __restrict__ bh, const float* __restrict__ br,
    const int* __restrict__ edge_src, const int* __restrict__ edge_dst,
    const int* __restrict__ edge_pred, const int* __restrict__ node_in,
    const int* __restrict__ step_eid, const int* __restrict__ step_v,
    int P, int Dn,
    float* __restrict__ m_, float* __restrict__ rm, unsigned short* __restrict__ hb)
{
  __shared__ unsigned short A1s[16*SROW];   // [sx|s]  -> after gate: [dx|m_new]
  __shared__ unsigned short A2s[16*SROW];   // [sx|arm]
  __shared__ int s_eoff[16], s_soff[16], s_doff[16];
  __shared__ int s_poff[16][MAXP];
  __shared__ int s_noff[16][MAXD];

  const int tid = threadIdx.x;
  const int wv = tid >> 6, lane = tid & 63;
  const int l15 = lane & 15, kh = lane >> 4;
  const int ko = kh*8;
  const int r0 = blockIdx.x * 16;

  // per-wave B pointers (K-major, 512 rows each, zero-padded)
  const unsigned short* pBz0 = WzT   + (size_t)(wv*32 + l15)*KP;
  const unsigned short* pBz1 = pBz0 + (size_t)16*KP;
  const unsigned short* pBh0 = WhT   + (size_t)(wv*32 + l15)*KP;
  const unsigned short* pBh1 = pBh0 + (size_t)16*KP;
  const unsigned short* pBr0 = WrUrT + (size_t)(wv*32 + l15)*KP;
  const unsigned short* pBr1 = pBr0 + (size_t)16*KP;
  const unsigned short* aB1 = &A1s[l15*SROW];
  const unsigned short* aB2 = &A2s[l15*SROW];

  for (int t = 0; t < T_; ++t){
    __syncthreads();                       // prev rgate epilogue done with s_* metadata
    if (tid < 16){
      int b = r0 + tid;
      int e = step_eid[t*B_ + b];
      s_eoff[tid] = e*H_;
      s_soff[tid] = edge_src[e]*H_;
      s_doff[tid] = edge_dst[e]*H_;
      int v = step_v[t*B_ + b];
      for (int q = 0; q < P; ++q) s_poff[tid][q] = edge_pred[e*P + q]*H_;
      for (int d = 0; d < Dn; ++d) s_noff[tid][d] = node_in[v*Dn + d]*H_;
    }
    __syncthreads();                       // metadata ready

    // ---- prep: A1=[sx|s], A2=[sx|arm] ----
    for (int idx = tid; idx < 3600; idx += 1024){
      int r = idx / 225, j2 = idx - r*225;
      int j = 2*j2;
      float2 sx = *(const float2*)(x + s_soff[r] + j);
      float2 s = {0.f,0.f}, ar = {0.f,0.f};
      for (int q = 0; q < P; ++q){
        float2 mv = *(const float2*)(m_ + s_poff[r][q] + j);
        float2 rv = *(const float2*)(rm + s_poff[r][q] + j);
        s.x += mv.x; s.y += mv.y; ar.x += rv.x; ar.y += rv.y;
      }
      unsigned int sxp = pack2(sx.x, sx.y);
      ((unsigned int*)(A1s + r*SROW))[j2] = sxp;
      ((unsigned int*)(A2s + r*SROW))[j2] = sxp;
      ((unsigned int*)(A1s + r*SROW + 450))[j2] = pack2(s.x, s.y);
      ((unsigned int*)(A2s + r*SROW + 450))[j2] = pack2(ar.x, ar.y);
    }
    for (int idx = tid; idx < 16*14; idx += 1024){   // zero K-pads [900,928)
      int r = idx / 14, u = idx - r*14;
      ((unsigned int*)(A1s + r*SROW + 900))[u] = 0u;
      ((unsigned int*)(A2s + r*SROW + 900))[u] = 0u;
    }
    __syncthreads();                       // A tiles ready

    // ---- gate K-loop: Z = A1@Wz, H = A2@Wh (B direct from global/L2) ----
    f32x4 accZ0 = {}, accZ1 = {}, accH0 = {}, accH1 = {};
    for (int kt = 0; kt < KP; kt += 32){
      bf16x8 a1 = *(const bf16x8*)(aB1 + kt + ko);
      bf16x8 a2 = *(const bf16x8*)(aB2 + kt + ko);
      bf16x8 b0 = *(const bf16x8*)(pBz0 + kt + ko);
      bf16x8 b1 = *(const bf16x8*)(pBz1 + kt + ko);
      bf16x8 b2 = *(const bf16x8*)(pBh0 + kt + ko);
      bf16x8 b3 = *(const bf16x8*)(pBh1 + kt + ko);
      accZ0 = __builtin_amdgcn_mfma_f32_16x16x32_bf16(a1,b0,accZ0,0,0,0);
      accZ1 = __builtin_amdgcn_mfma_f32_16x16x32_bf16(a1,b1,accZ1,0,0,0);
      accH0 = __builtin_amdgcn_mfma_f32_16x16x32_bf16(a2,b2,accH0,0,0,0);
      accH1 = __builtin_amdgcn_mfma_f32_16x16x32_bf16(a2,b3,accH1,0,0,0);
    }
    __syncthreads();                       // all waves done reading A1s/A2s

    // ---- gate epilogue: m_new; A1s becomes [dx|m_new] ----
    #pragma unroll
    for (int ct = 0; ct < 2; ++ct){
      int c = wv*32 + ct*16 + l15;
      if (c < H_){
        float bzc = bz[c], bhc = bh[c];
        f32x4 aZ = ct ? accZ1 : accZ0;
        f32x4 aH = ct ? accH1 : accH0;
        #pragma unroll
        for (int reg = 0; reg < 4; ++reg){
          int row = kh*4 + reg;
          float z  = sigmoidf_(aZ[reg] + bzc);
          float th = tanhf(aH[reg] + bhc);
          float s  = b2f(A1s[row*SROW + 450 + c]);
          float mn = (1.f - z)*s + z*th;
          m_[s_eoff[row] + c] = mn;                 // f32 state write
          A1s[row*SROW + 450 + c] = f2b(mn);        // A3 second half
        }
      }
    }
    // dx fill into A1s[:,0:450) (region dead after gate K-loop)
    for (int idx = tid; idx < 3600; idx += 1024){
      int r = idx / 225, j2 = idx - r*225;
      float2 dx = *(const float2*)(x + s_doff[r] + 2*j2);
      ((unsigned int*)(A1s + r*SROW))[j2] = pack2(dx.x, dx.y);
    }
    __syncthreads();                       // A3 ready

    // ---- rgate K-loop: R = [dx|m_new]@[Wr;Ur] ----
    f32x4 accR0 = {}, accR1 = {};
    for (int kt = 0; kt < KP; kt += 32){
      bf16x8 a = *(const bf16x8*)(aB1 + kt + ko);
      bf16x8 b0 = *(const bf16x8*)(pBr0 + kt + ko);
      bf16x8 b1 = *(const bf16x8*)(pBr1 + kt + ko);
      accR0 = __builtin_amdgcn_mfma_f32_16x16x32_bf16(a,b0,accR0,0,0,0);
      accR1 = __builtin_amdgcn_mfma_f32_16x16x32_bf16(a,b1,accR1,0,0,0);
    }
    __syncthreads();                       // done reading A1s (next prep may rewrite)

    // ---- rgate epilogue: rm, h-pull ----
    #pragma unroll
    for (int ct = 0; ct < 2; ++ct){
      int c = wv*32 + ct*16 + l15;
      if (c < H_){
        float brc = br[c];
        f32x4 aR = ct ? accR1 : accR0;
        #pragma unroll
        for (int reg = 0; reg < 4; ++reg){
          int row = kh*4 + reg;
          float r_ = sigmoidf_(aR[reg] + brc);
          float mn = m_[s_eoff[row] + c];
          rm[s_eoff[row] + c] = r_*mn;
          float h = 0.f;
          for (int d = 0; d < Dn; ++d) h += m_[s_noff[row][d] + c];
          hb[(size_t)(t*B_ + r0 + row)*H_ + c] = f2b(h);
        }
      }
    }
  }
}

// ---------------------------------------------------------------------------
// MFMA tile core for heads: 64x64 tile, 4 waves (2x2), BK=32, K-major bf16.
__device__ __forceinline__ void mfma_tile_core(
    const unsigned short* __restrict__ A, const unsigned short* __restrict__ BT,
    int K, int gr0, int gc0, int tid,
    unsigned short* __restrict__ As, unsigned short* __restrict__ Bs,
    f32x4 (&acc)[2][2])
{
  const int lane = tid & 63;
  const int w = tid >> 6, wr = w >> 1, wc = w & 1;
  const int l15 = lane & 15, kh = lane >> 4;
  const int sr = tid >> 2, sj = (tid & 3) * 8;
  const size_t arow = (size_t)(gr0 + sr) * K;
  const size_t brow = (size_t)(gc0 + sr) * K;
  for (int kt = 0; kt < K; kt += 32){
    __syncthreads();
    *(float4*)&As[sr*40 + sj] = *(const float4*)&A[arow + kt + sj];
    *(float4*)&Bs[sr*40 + sj] = *(const float4*)&BT[brow + kt + sj];
    __syncthreads();
    bf16x8 a0 = *(const bf16x8*)&As[(wr*32      + l15)*40 + kh*8];
    bf16x8 a1 = *(const bf16x8*)&As[(wr*32 + 16 + l15)*40 + kh*8];
    bf16x8 b0 = *(const bf16x8*)&Bs[(wc*32      + l15)*40 + kh*8];
    bf16x8 b1 = *(const bf16x8*)&Bs[(wc*32 + 16 + l15)*40 + kh*8];
    acc[0][0] = __builtin_amdgcn_mfma_f32_16x16x32_bf16(a0,b0,acc[0][0],0,0,0);
    acc[0][1] = __builtin_amdgcn_mfma_f32_16x16x32_bf16(a0,b1,acc[0][1],0,0,0);
    acc[1][0] = __builtin_amdgcn_mfma_f32_16x16x32_bf16(a1,b0,acc[1][0],0,0,0);
    acc[1][1] = __builtin_amdgcn_mfma_f32_16x16x32_bf16(a1,b1,acc[1][1],0,0,0);
  }
}

// Head GEMM: C = act(A@B + bias); f32 store (c<Nact) and/or bf16 store (pads zeroed).
__global__ __launch_bounds__(256) void k_head_mfma(
    const unsigned short* __restrict__ A, const unsigned short* __restrict__ BT, int K,
    const float* __restrict__ bias, int Nact, int relu,
    float* __restrict__ outF, int ldF, unsigned short* __restrict__ outB, int ldB)
{
  __shared__ unsigned short As[64*40], Bs[64*40];
  const int tid = threadIdx.x;
  const int gr0 = blockIdx.y*64, gc0 = blockIdx.x*64;
  f32x4 acc[2][2] = {};
  mfma_tile_core(A, BT, K, gr0, gc0, tid, As, Bs, acc);
  const int lane = tid & 63;
  const int w = tid >> 6, wr = w >> 1, wc = w & 1;
  const int l15 = lane & 15, kh = lane >> 4;
  #pragma unroll
  for (int mi = 0; mi < 2; ++mi){
    #pragma unroll
    for (int n = 0; n < 2; ++n){
      int c = gc0 + wc*32 + n*16 + l15;
      float bc = (c < Nact) ? bias[c] : 0.f;
      #pragma unroll
      for (int reg = 0; reg < 4; ++reg){
        int r = gr0 + wr*32 + mi*16 + kh*4 + reg;
        float v = acc[mi][n][reg] + bc;
        if (relu) v = fmaxf(v, 0.f);
        if (outF && c < Nact) outF[(size_t)r*ldF + c] = v;
        if (outB && c < ldB)  outB[(size_t)r*ldB + c] = (c < Nact) ? f2b(v) : (unsigned short)0;
      }
    }
  }
}

// p-head GEMM with fused Us-dot: plog[r] += sum_c relu(acc+bu)*Us[c]
__global__ __launch_bounds__(256) void k_head_p(
    const unsigned short* __restrict__ A, const unsigned short* __restrict__ BT,
    const float* __restrict__ bu_, const float* __restrict__ Us, float* __restrict__ plog)
{
  __shared__ unsigned short As[64*40], Bs[64*40];
  const int tid = threadIdx.x;
  const int gr0 = blockIdx.y*64, gc0 = blockIdx.x*64;
  f32x4 acc[2][2] = {};
  mfma_tile_core(A, BT, 960, gr0, gc0, tid, As, Bs, acc);
  const int lane = tid & 63;
  const int w = tid >> 6, wr = w >> 1, wc = w & 1;
  const int l15 = lane & 15, kh = lane >> 4;
  #pragma unroll
  for (int mi = 0; mi < 2; ++mi){
    float rowsum[4] = {0.f,0.f,0.f,0.f};
    #pragma unroll
    for (int n = 0; n < 2; ++n){
      int c = gc0 + wc*32 + n*16 + l15;
      float uc = 0.f, bc = 0.f;
      if (c < H_){ uc = Us[c]; bc = bu_[c]; }
      #pragma unroll
      for (int reg = 0; reg < 4; ++reg){
        float v = fmaxf(acc[mi][n][reg] + bc, 0.f);
        rowsum[reg] += (c < H_) ? v*uc : 0.f;
      }
    }
    #pragma unroll
    for (int reg = 0; reg < 4; ++reg){
      float p = rowsum[reg];
      p += __shfl_xor(p,1); p += __shfl_xor(p,2);
      p += __shfl_xor(p,4); p += __shfl_xor(p,8);
      if (l15 == 0) atomicAdd(plog + gr0 + wr*32 + mi*16 + kh*4 + reg, p);
    }
  }
}

// ---------------------------------------------------------------------------
// Builders (wave-per-row, vectorized, write pads -> no big memsets needed)
__global__ __launch_bounds__(256) void k_build_Aq(const unsigned short* __restrict__ hb,
    const float* __restrict__ tv, const int* __restrict__ q_rows,
    unsigned short* __restrict__ Aq, int nq){
  int w = blockIdx.x*4 + (threadIdx.x>>6), lane = threadIdx.x & 63;
  int nw = gridDim.x*4;
  for (int i = w; i < nq; i += nw){
    int row = q_rows[i]; int b = row & (B_-1);
    unsigned short* dst = Aq + (size_t)i*512;
    if (row < B_){
      for (int j2 = lane; j2 < 225; j2 += 64) ((unsigned int*)dst)[j2] = 0u;
    } else {
      const unsigned int* src = (const unsigned int*)(hb + (size_t)(row-B_)*H_);
      for (int j2 = lane; j2 < 225; j2 += 64) ((unsigned int*)dst)[j2] = src[j2];
    }
    int k = 450 + lane;
    if (k < 512){
      unsigned short v = 0;
      if (k < 506) v = f2b(tv[b*L_ + (k-450)]);
      dst[k] = v;
    }
  }
}

__global__ __launch_bounds__(256) void k_build_Ap(const unsigned short* __restrict__ hb,
    const float* __restrict__ x, const float* __restrict__ tv,
    const int* __restrict__ root_ids, const int* __restrict__ step_v,
    unsigned short* __restrict__ Ap){
  int w = blockIdx.x*4 + (threadIdx.x>>6), lane = threadIdx.x & 63;
  int nw = gridDim.x*4;
  for (int i = w; i < NPROWS; i += nw){
    int b = i & (B_-1);
    unsigned short* dst = Ap + (size_t)i*960;
    int xn = (i < B_) ? root_ids[b] : step_v[i - B_];
    const float2* xr = (const float2*)(x + (size_t)xn*H_);
    for (int j2 = lane; j2 < 225; j2 += 64){
      float2 v = xr[j2];
      ((unsigned int*)dst)[j2] = pack2(v.x, v.y);
    }
    if (i < B_){
      for (int j2 = lane; j2 < 225; j2 += 64) ((unsigned int*)(dst + 450))[j2] = 0u;
    } else {
      const unsigned int* hr = (const unsigned int*)(hb + (size_t)(i-B_)*H_);
      for (int j2 = lane; j2 < 225; j2 += 64) ((unsigned int*)(dst + 450))[j2] = hr[j2];
    }
    int k = 900 + lane;
    if (k < 960){
      unsigned short v = 0;
      if (k < 956) v = f2b(tv[b*L_ + (k-900)]);
      dst[k] = v;
    }
  }
}

// ---------------------------------------------------------------------------
// q reduce: wave-per-row, register-cached row, shuffle reductions
__global__ __launch_bounds__(256) void k_qreduce2(const float* __restrict__ logits,
    const int* __restrict__ q_tgt, int nq, float* __restrict__ out){
  int w = blockIdx.x*4 + (threadIdx.x>>6), lane = threadIdx.x & 63;
  int nw = gridDim.x*4;
  float qloss = 0.f, qacc = 0.f;
  for (int i = w; i < nq; i += nw){
    const float4* lr4 = (const float4*)(logits + (size_t)i*V_);
    float4 vals[4]; int cnt = 0;
    float mx = -INFINITY; int mi = 0x7fffffff;
    for (int j4 = lane; j4 < 195; j4 += 64){
      float4 v = lr4[j4]; vals[cnt++] = v;
      #pragma unroll
      for (int u = 0; u < 4; ++u){
        float f = ((float*)&v)[u];
        if (f > mx){ mx = f; mi = j4*4 + u; }
      }
    }
    #pragma unroll
    for (int off = 32; off; off >>= 1){
      float omx = __shfl_xor(mx, off); int omi = __shfl_xor(mi, off);
      if (omx > mx || (omx == mx && omi < mi)){ mx = omx; mi = omi; }
    }
    float ps = 0.f; cnt = 0;
    for (int j4 = lane; j4 < 195; j4 += 64){
      float4 v = vals[cnt++];
      ps += expf(v.x-mx) + expf(v.y-mx) + expf(v.z-mx) + expf(v.w-mx);
    }
    #pragma unroll
    for (int off = 32; off; off >>= 1) ps += __shfl_xor(ps, off);
    if (lane == 0){
      int tg = q_tgt[i];
      float lt = logits[(size_t)i*V_ + tg];
      qloss += mx + logf(ps) - lt;
      qacc  += (mi == tg) ? 1.f : 0.f;
    }
  }
  if (lane == 0){
    atomicAdd(out+0, qloss*(1.0f/B_));
    atomicAdd(out+2, qacc *(1.0f/(float)nq));
  }
}

// p final: BCE + acc from plog
__global__ __launch_bounds__(256) void k_pfinal(const float* __restrict__ plog,
    const float* __restrict__ bs, const int* __restrict__ p_tgt, float* __restrict__ out){
  int i = blockIdx.x*256 + threadIdx.x;
  float loss = 0.f, acc = 0.f;
  if (i < NPROWS){
    float pl = plog[i] + bs[0];
    float tgt = (float)p_tgt[i];
    loss = fmaxf(pl, 0.f) + log1pf(expf(-fabsf(pl))) - pl*tgt;
    acc = (((pl > 0.f) ? 1 : 0) == p_tgt[i]) ? 1.f : 0.f;
  }
  #pragma unroll
  for (int off = 32; off; off >>= 1){
    loss += __shfl_xor(loss, off); acc += __shfl_xor(acc, off);
  }
  if ((threadIdx.x & 63) == 0){
    atomicAdd(out+1, loss*(1.0f/B_));
    atomicAdd(out+3, acc *(1.0f/(float)NPROWS));
  }
}

// ---------------------------------------------------------------------------
extern "C" void kernel_launch(void* const* d_in, const int* in_sizes, int n_in,
                              void* d_out, int out_size, void* d_ws, size_t ws_size,
                              hipStream_t stream){
  const float* tree_vec = (const float*)d_in[0];
  const float* emb  = (const float*)d_in[1];
  const float* Wz   = (const float*)d_in[2];
  const float* bz   = (const float*)d_in[3];
  const float* Wh   = (const float*)d_in[4];
  const float* bh   = (const float*)d_in[5];
  const float* Wr   = (const float*)d_in[6];
  const float* Ur   = (const float*)d_in[7];
  const float* br   = (const float*)d_in[8];
  const float* Ww   = (const float*)d_in[9];
  const float* bw   = (const float*)d_in[10];
  const float* Uw   = (const float*)d_in[11];
  const float* bu   = (const float*)d_in[12];
  const float* Wo   = (const float*)d_in[13];
  const float* bo   = (const float*)d_in[14];
  const float* Us   = (const float*)d_in[15];
  const float* bs   = (const float*)d_in[16];
  const int* wid      = (const int*)d_in[17];
  const int* root_ids = (const int*)d_in[18];
  const int* edge_src = (const int*)d_in[19];
  const int* edge_dst = (const int*)d_in[20];
  const int* edge_pred= (const int*)d_in[21];
  const int* node_in  = (const int*)d_in[22];
  const int* step_eid = (const int*)d_in[23];
  const int* step_v   = (const int*)d_in[24];
  const int* q_rows   = (const int*)d_in[25];
  const int* q_tgt    = (const int*)d_in[26];
  const int* p_tgt    = (const int*)d_in[27];
  int P  = in_sizes[21] / NEDGES;  if (P > MAXP) P = MAXP;
  int Dn = in_sizes[22] / NNODES;  if (Dn > MAXD) Dn = MAXD;
  int nq = in_sizes[25];           // 10240

  char* ws = (char*)d_ws;
  // --- fixed layout ---
  const size_t X_OFF   = 0;                        // f32 [10240][450]
  const size_t HB_OFF  = 18432000;                 // bf16 [T*B][450]
  const size_t M_OFF   = 35942400;                 // f32 [(E+1)][450] (pad to 35,022,848)
  const size_t RM_OFF  = M_OFF + 35022848;
  const size_t W_OFF   = RM_OFF + 35022848;        // weights after state
  const size_t WZT_OFF = W_OFF;                    // bf16 [512][928]
  const size_t WHT_OFF = WZT_OFF + 950272;
  const size_t WRT_OFF = WHT_OFF + 950272;
  const size_t WWT_OFF = WRT_OFF + 950272;         // bf16 [512][512]
  const size_t UWT_OFF = WWT_OFF + 524288;         // bf16 [512][960]
  const size_t WOT_OFF = UWT_OFF + 983040;         // bf16 [832][512]
  // overlays in dead m/rm region after scan:
  const size_t AQ_OFF  = M_OFF;                    // bf16 [10240][512] = 10,485,760
  const size_t LQ_OFF  = M_OFF + 10485760;         // f32 [10240][780] = 31,948,800
  const size_t HQB_OFF = M_OFF + 42434560;         // bf16 [10240][512] = 10,485,760
  const size_t PL_OFF  = M_OFF + 52920320;         // f32 [19968] = 79,872
  const size_t AP_OFF  = M_OFF;                    // bf16 [19968][960] = 38,338,560

  float* x  = (float*)(ws + X_OFF);
  unsigned short* hb = (unsigned short*)(ws + HB_OFF);
  float* m_ = (float*)(ws + M_OFF);
  float* rm = (float*)(ws + RM_OFF);
  unsigned short* WzT = (unsigned short*)(ws + WZT_OFF);
  unsigned short* WhT = (unsigned short*)(ws + WHT_OFF);
  unsigned short* WrUrT = (unsigned short*)(ws + WRT_OFF);
  unsigned short* WwT = (unsigned short*)(ws + WWT_OFF);
  unsigned short* UwT = (unsigned short*)(ws + UWT_OFF);
  unsigned short* WoT = (unsigned short*)(ws + WOT_OFF);

  // zero init: m/rm (sentinel + unvisited-edge rows), out
  hipMemsetAsync(ws + M_OFF, 0, 2*35022848ull, stream);
  hipMemsetAsync(d_out, 0, (size_t)out_size*sizeof(float), stream);

  k_gather_x<<<2560, 256, 0, stream>>>(emb, wid, x);

  k_wt<<<512, 256, 0, stream>>>(Wz, Wz, 900, 900, 450, WzT, KP);
  k_wt<<<512, 256, 0, stream>>>(Wh, Wh, 900, 900, 450, WhT, KP);
  k_wt<<<512, 256, 0, stream>>>(Wr, Ur, 450, 900, 450, WrUrT, KP);
  k_wt<<<512, 256, 0, stream>>>(Ww, Ww, 506, 506, 450, WwT, 512);
  k_wt<<<512, 256, 0, stream>>>(Uw, Uw, 956, 956, 450, UwT, 960);
  k_wt<<<832, 256, 0, stream>>>(Wo, Wo, 450, 450, 780, WoT, 512);

  // ---- fused 38-step scan: ONE kernel, no cross-block deps ----
  k_scan_all<<<32, 1024, 0, stream>>>(x, WzT, WhT, WrUrT, bz, bh, br,
      edge_src, edge_dst, edge_pred, node_in, step_eid, step_v, P, Dn,
      m_, rm, hb);

  // ---- q head ----
  unsigned short* Aq  = (unsigned short*)(ws + AQ_OFF);
  float* logitsq      = (float*)(ws + LQ_OFF);
  unsigned short* hqb = (unsigned short*)(ws + HQB_OFF);
  float* plog         = (float*)(ws + PL_OFF);
  hipMemsetAsync(plog, 0, (size_t)NPROWS*4, stream);

  k_build_Aq<<<640, 256, 0, stream>>>(hb, tree_vec, q_rows, Aq, nq);
  k_head_mfma<<<dim3(8, nq/64), 256, 0, stream>>>(Aq, WwT, 512, bw, H_, 1,
      nullptr, 0, hqb, 512);
  k_head_mfma<<<dim3(13, nq/64), 256, 0, stream>>>(hqb, WoT, 512, bo, V_, 0,
      logitsq, V_, nullptr, 0);
  k_qreduce2<<<320, 256, 0, stream>>>(logitsq, q_tgt, nq, (float*)d_out);

  // ---- p head (reuses M region; q buffers dead except plog which sits above) ----
  unsigned short* Ap = (unsigned short*)(ws + AP_OFF);
  k_build_Ap<<<1248, 256, 0, stream>>>(hb, x, tree_vec, root_ids, step_v, Ap);
  k_head_p<<<dim3(8, NPROWS/64), 256, 0, stream>>>(Ap, UwT, bu, Us, plog);
  k_pfinal<<<78, 256, 0, stream>>>(plog, bs, p_tgt, (float*)d_out);
}

// Round 6
// 2570.538 us; speedup vs baseline: 1.4664x; 1.4664x over previous
//
#include <hip/hip_runtime.h>
#include <hip/hip_cooperative_groups.h>
#include <math.h>

namespace cg = cooperative_groups;

#define B_ 512
#define N_ 20
#define H_ 450
#define L_ 56
#define V_ 780
#define T_ 38
#define NNODES (B_*N_)        // 10240
#define NEDGES (B_*2*(N_-1))  // 19456
#define NPROWS ((T_+1)*B_)    // 19968
#define MAXP 8
#define MAXD 8
#define KS 480                // scan K pad (450 -> 480 = 15*32); also m/rm row stride
#define AST 488               // A-tile LDS row stride in shorts (976B -> 2-way banks)

typedef __attribute__((ext_vector_type(8))) short bf16x8;
typedef __attribute__((ext_vector_type(4))) float f32x4;

__device__ __forceinline__ float sigmoidf_(float v){ return 1.0f/(1.0f+expf(-v)); }

__device__ __forceinline__ unsigned short f2b(float x){
  unsigned int u = __float_as_uint(x);
  unsigned int r = (u + 0x7fffu + ((u >> 16) & 1u)) >> 16;
  return (unsigned short)r;
}
__device__ __forceinline__ float b2f(unsigned short v){
  return __uint_as_float((unsigned int)v << 16);
}
__device__ __forceinline__ unsigned int pack2(float lo, float hi){
  return (unsigned int)f2b(lo) | ((unsigned int)f2b(hi) << 16);
}

// ---------------------------------------------------------------------------
// xb[i][:] = bf16(emb[wid[i]][:]), K-padded to 480
__global__ __launch_bounds__(256) void k_gather_xb(const float* __restrict__ emb,
    const int* __restrict__ wid, unsigned short* __restrict__ xb){
  int w = blockIdx.x*4 + (threadIdx.x>>6), lane = threadIdx.x & 63;
  if (w >= NNODES) return;
  const float2* src = (const float2*)(emb + (size_t)wid[w]*H_);
  unsigned int* dst = (unsigned int*)(xb + (size_t)w*KS);
  for (int j2 = lane; j2 < 240; j2 += 64){
    unsigned int v = 0;
    if (j2 < 225){ float2 f = src[j2]; v = pack2(f.x, f.y); }
    dst[j2] = v;
  }
}

// Transpose+convert weight to K-major bf16 with zero padding.
__global__ void k_wt(const float* __restrict__ W1, const float* __restrict__ W2,
                     int Ksplit, int Kact, int Nact, unsigned short* __restrict__ dst, int Kpad){
  int c = blockIdx.x;
  unsigned short* drow = dst + (size_t)c*Kpad;
  for (int k = threadIdx.x; k < Kpad; k += blockDim.x){
    float v = 0.f;
    if (c < Nact && k < Kact)
      v = (k < Ksplit) ? W1[(size_t)k*Nact + c] : W2[(size_t)(k-Ksplit)*Nact + c];
    drow[k] = f2b(v);
  }
}

// ---------------------------------------------------------------------------
struct ScanP {
  const unsigned short *WzB, *WhB, *UrT;        // [512][480] K-major bf16 (bottom/Ur)
  const unsigned short *XWz, *XWh, *XWr;        // [10240][450] bf16, bias folded in
  const int *edge_src, *edge_dst, *edge_pred, *node_in, *step_eid, *step_v;
  unsigned short *m, *rm, *hb;                  // m/rm [NEDGES+1][480], hb [T*B][450]
  int P, Dn;
};

// Cooperative scan: 64 blocks = 8 tree-tiles x 8 col-tiles, 1024 thr (16 waves 4x4).
// Per step: gather A(LDS) -> gate MFMA -> m write -> gsync -> rgate -> rm/h -> gsync.
__global__ __launch_bounds__(1024,1) void k_scan_coop(ScanP p){
  cg::grid_group grid = cg::this_grid();
  __shared__ unsigned short A1s[64*AST];        // [s]   rows=trees
  __shared__ unsigned short A2s[64*AST];        // [arm]
  __shared__ unsigned short Bs1[2][64*40];      // dbuf tiles
  __shared__ unsigned short Bs2[2][64*40];
  __shared__ int s_moff[64], s_src[64], s_dst[64], s_pcnt[64], s_dcnt[64];
  __shared__ int s_poff[64][MAXP];
  __shared__ int s_noff[64][MAXD];

  const int tid = threadIdx.x;
  const int lane = tid & 63, l15 = lane & 15, kh = lane >> 4;
  const int wv = tid >> 6, wr = wv >> 2, wc = wv & 3;
  const int by = blockIdx.x >> 3, bx = blockIdx.x & 7;
  const int r0 = by*64, c0 = bx*64;
  const int P = p.P, Dn = p.Dn;
  const int st_r = (tid & 255) >> 2, st_j = (tid & 3) * 8;
  const int gr = tid >> 4, gsub = tid & 15;     // gather: 16 threads per tree row
  const int cc = c0 + wc*16 + l15;

  for (int t = 0; t < T_; ++t){
    // ---- per-step metadata (compacted pred/node lists) ----
    if (tid < 64){
      int b = r0 + tid;
      int e = p.step_eid[t*B_ + b];
      s_moff[tid] = e*KS;
      s_src[tid] = p.edge_src[e]*H_;
      s_dst[tid] = p.edge_dst[e]*H_;
      int pc = 0;
      for (int q = 0; q < P; ++q){
        int pe = p.edge_pred[e*P + q];
        if (pe != NEDGES) s_poff[tid][pc++] = pe*KS;
      }
      s_pcnt[tid] = pc;
      int v = p.step_v[t*B_ + b];
      int dc = 0;
      for (int d = 0; d < Dn; ++d){
        int ne = p.node_in[v*Dn + d];
        if (ne != NEDGES) s_noff[tid][dc++] = ne*KS;
      }
      s_dcnt[tid] = dc;
    }
    __syncthreads();

    // ---- gather A1=[s], A2=[arm] into LDS (bf16), pads zero ----
    {
      int pc = s_pcnt[gr];
      for (int j2 = gsub; j2 < 240; j2 += 16){
        float sx_=0.f, sy_=0.f, ax_=0.f, ay_=0.f;
        if (j2 < 225){
          for (int q = 0; q < pc; ++q){
            int o = s_poff[gr][q] + 2*j2;
            unsigned int mv = *(const unsigned int*)(p.m + o);
            unsigned int rv = *(const unsigned int*)(p.rm + o);
            sx_ += b2f((unsigned short)(mv & 0xffff)); sy_ += b2f((unsigned short)(mv >> 16));
            ax_ += b2f((unsigned short)(rv & 0xffff)); ay_ += b2f((unsigned short)(rv >> 16));
          }
        }
        ((unsigned int*)(A1s + gr*AST))[j2] = pack2(sx_, sy_);
        ((unsigned int*)(A2s + gr*AST))[j2] = pack2(ax_, ay_);
      }
    }
    __syncthreads();

    // ---- gate K-loop: Z = s@WzB, H = arm@WhB (dbuf B tiles) ----
    if (tid < 512){
      const unsigned short* src = (tid < 256) ? p.WzB : p.WhB;
      unsigned short* d = (tid < 256) ? Bs1[0] : Bs2[0];
      *(float4*)&d[st_r*40 + st_j] = *(const float4*)&src[(size_t)(c0+st_r)*KS + st_j];
    }
    __syncthreads();
    f32x4 accZ = {}, accH = {};
    for (int it = 0; it < 15; ++it){
      int cur = it & 1;
      if (it < 14 && tid < 512){
        const unsigned short* src = (tid < 256) ? p.WzB : p.WhB;
        unsigned short* d = (tid < 256) ? Bs1[cur^1] : Bs2[cur^1];
        *(float4*)&d[st_r*40 + st_j] = *(const float4*)&src[(size_t)(c0+st_r)*KS + (it+1)*32 + st_j];
      }
      bf16x8 a1 = *(const bf16x8*)&A1s[(wr*16+l15)*AST + it*32 + kh*8];
      bf16x8 a2 = *(const bf16x8*)&A2s[(wr*16+l15)*AST + it*32 + kh*8];
      bf16x8 b1 = *(const bf16x8*)&Bs1[cur][(wc*16+l15)*40 + kh*8];
      bf16x8 b2 = *(const bf16x8*)&Bs2[cur][(wc*16+l15)*40 + kh*8];
      accZ = __builtin_amdgcn_mfma_f32_16x16x32_bf16(a1,b1,accZ,0,0,0);
      accH = __builtin_amdgcn_mfma_f32_16x16x32_bf16(a2,b2,accH,0,0,0);
      __syncthreads();
    }

    // ---- gate epilogue: m[eid] = (1-z)*s + z*tanh(...) (bf16) ----
    if (cc < H_){
      #pragma unroll
      for (int reg = 0; reg < 4; ++reg){
        int rl = wr*16 + kh*4 + reg;
        float z  = sigmoidf_(accZ[reg] + b2f(p.XWz[s_src[rl] + cc]));
        float th = tanhf   (accH[reg] + b2f(p.XWh[s_src[rl] + cc]));
        float s_ = 0.f;
        int pc = s_pcnt[rl];
        for (int q = 0; q < pc; ++q) s_ += b2f(p.m[s_poff[rl][q] + cc]);
        float mn = (1.f - z)*s_ + z*th;
        p.m[s_moff[rl] + cc] = f2b(mn);
      }
    }
    grid.sync();   // m_new complete across all col-tiles

    // ---- rgate K-loop: R = m_new@Ur (A staged from global m rows) ----
    if (tid < 512){
      const float4 v = (tid < 256)
        ? *(const float4*)&p.m[s_moff[st_r] + st_j]
        : *(const float4*)&p.UrT[(size_t)(c0+st_r)*KS + st_j];
      unsigned short* d = (tid < 256) ? Bs1[0] : Bs2[0];
      *(float4*)&d[st_r*40 + st_j] = v;
    }
    __syncthreads();
    f32x4 accR = {};
    for (int it = 0; it < 15; ++it){
      int cur = it & 1;
      if (it < 14 && tid < 512){
        const float4 v = (tid < 256)
          ? *(const float4*)&p.m[s_moff[st_r] + (it+1)*32 + st_j]
          : *(const float4*)&p.UrT[(size_t)(c0+st_r)*KS + (it+1)*32 + st_j];
        unsigned short* d = (tid < 256) ? Bs1[cur^1] : Bs2[cur^1];
        *(float4*)&d[st_r*40 + st_j] = v;
      }
      bf16x8 a = *(const bf16x8*)&Bs1[cur][(wr*16+l15)*40 + kh*8];
      bf16x8 b = *(const bf16x8*)&Bs2[cur][(wc*16+l15)*40 + kh*8];
      accR = __builtin_amdgcn_mfma_f32_16x16x32_bf16(a,b,accR,0,0,0);
      __syncthreads();
    }

    // ---- rgate epilogue: rm, h-pull ----
    if (cc < H_){
      #pragma unroll
      for (int reg = 0; reg < 4; ++reg){
        int rl = wr*16 + kh*4 + reg;
        float r_ = sigmoidf_(accR[reg] + b2f(p.XWr[s_dst[rl] + cc]));
        float mn = b2f(p.m[s_moff[rl] + cc]);
        p.rm[s_moff[rl] + cc] = f2b(r_*mn);
        float h = 0.f;
        int dc = s_dcnt[rl];
        for (int d = 0; d < dc; ++d) h += b2f(p.m[s_noff[rl][d] + cc]);
        p.hb[(size_t)(t*B_ + r0 + rl)*H_ + cc] = f2b(h);
      }
    }
    grid.sync();   // rm complete -> next step's gather
  }
}

// ---------------------------------------------------------------------------
// MFMA tile core for heads: 64x64 tile, 4 waves (2x2), BK=32, K-major bf16.
__device__ __forceinline__ void mfma_tile_core(
    const unsigned short* __restrict__ A, const unsigned short* __restrict__ BT,
    int K, int gr0, int gc0, int tid,
    unsigned short* __restrict__ As, unsigned short* __restrict__ Bs,
    f32x4 (&acc)[2][2])
{
  const int lane = tid & 63;
  const int w = tid >> 6, wr = w >> 1, wc = w & 1;
  const int l15 = lane & 15, kh = lane >> 4;
  const int sr = tid >> 2, sj = (tid & 3) * 8;
  const size_t arow = (size_t)(gr0 + sr) * K;
  const size_t brow = (size_t)(gc0 + sr) * K;
  for (int kt = 0; kt < K; kt += 32){
    __syncthreads();
    *(float4*)&As[sr*40 + sj] = *(const float4*)&A[arow + kt + sj];
    *(float4*)&Bs[sr*40 + sj] = *(const float4*)&BT[brow + kt + sj];
    __syncthreads();
    bf16x8 a0 = *(const bf16x8*)&As[(wr*32      + l15)*40 + kh*8];
    bf16x8 a1 = *(const bf16x8*)&As[(wr*32 + 16 + l15)*40 + kh*8];
    bf16x8 b0 = *(const bf16x8*)&Bs[(wc*32      + l15)*40 + kh*8];
    bf16x8 b1 = *(const bf16x8*)&Bs[(wc*32 + 16 + l15)*40 + kh*8];
    acc[0][0] = __builtin_amdgcn_mfma_f32_16x16x32_bf16(a0,b0,acc[0][0],0,0,0);
    acc[0][1] = __builtin_amdgcn_mfma_f32_16x16x32_bf16(a0,b1,acc[0][1],0,0,0);
    acc[1][0] = __builtin_amdgcn_mfma_f32_16x16x32_bf16(a1,b0,acc[1][0],0,0,0);
    acc[1][1] = __builtin_amdgcn_mfma_f32_16x16x32_bf16(a1,b1,acc[1][1],0,0,0);
  }
}

// Head GEMM: C = act(A@B + bias); f32 store and/or bf16 store.
__global__ __launch_bounds__(256) void k_head_mfma(
    const unsigned short* __restrict__ A, const unsigned short* __restrict__ BT, int K,
    const float* __restrict__ bias, int Nact, int relu,
    float* __restrict__ outF, int ldF, unsigned short* __restrict__ outB, int ldB)
{
  __shared__ unsigned short As[64*40], Bs[64*40];
  const int tid = threadIdx.x;
  const int gr0 = blockIdx.y*64, gc0 = blockIdx.x*64;
  f32x4 acc[2][2] = {};
  mfma_tile_core(A, BT, K, gr0, gc0, tid, As, Bs, acc);
  const int lane = tid & 63;
  const int w = tid >> 6, wr = w >> 1, wc = w & 1;
  const int l15 = lane & 15, kh = lane >> 4;
  #pragma unroll
  for (int mi = 0; mi < 2; ++mi){
    #pragma unroll
    for (int n = 0; n < 2; ++n){
      int c = gc0 + wc*32 + n*16 + l15;
      float bc = (c < Nact) ? bias[c] : 0.f;
      #pragma unroll
      for (int reg = 0; reg < 4; ++reg){
        int r = gr0 + wr*32 + mi*16 + kh*4 + reg;
        float v = acc[mi][n][reg] + bc;
        if (relu) v = fmaxf(v, 0.f);
        if (outF && c < Nact) outF[(size_t)r*ldF + c] = v;
        if (outB && c < ldB)  outB[(size_t)r*ldB + c] = (c < Nact) ? f2b(v) : (unsigned short)0;
      }
    }
  }
}

// p-head GEMM with fused Us-dot: plog[r] += sum_c relu(acc+bu)*Us[c]
__global__ __launch_bounds__(256) void k_head_p(
    const unsigned short* __restrict__ A, const unsigned short* __restrict__ BT,
    const float* __restrict__ bu_, const float* __restrict__ Us, float* __restrict__ plog)
{
  __shared__ unsigned short As[64*40], Bs[64*40];
  const int tid = threadIdx.x;
  const int gr0 = blockIdx.y*64, gc0 = blockIdx.x*64;
  f32x4 acc[2][2] = {};
  mfma_tile_core(A, BT, 960, gr0, gc0, tid, As, Bs, acc);
  const int lane = tid & 63;
  const int w = tid >> 6, wr = w >> 1, wc = w & 1;
  const int l15 = lane & 15, kh = lane >> 4;
  #pragma unroll
  for (int mi = 0; mi < 2; ++mi){
    float rowsum[4] = {0.f,0.f,0.f,0.f};
    #pragma unroll
    for (int n = 0; n < 2; ++n){
      int c = gc0 + wc*32 + n*16 + l15;
      float uc = 0.f, bc = 0.f;
      if (c < H_){ uc = Us[c]; bc = bu_[c]; }
      #pragma unroll
      for (int reg = 0; reg < 4; ++reg){
        float v = fmaxf(acc[mi][n][reg] + bc, 0.f);
        rowsum[reg] += (c < H_) ? v*uc : 0.f;
      }
    }
    #pragma unroll
    for (int reg = 0; reg < 4; ++reg){
      float p = rowsum[reg];
      p += __shfl_xor(p,1); p += __shfl_xor(p,2);
      p += __shfl_xor(p,4); p += __shfl_xor(p,8);
      if (l15 == 0) atomicAdd(plog + gr0 + wr*32 + mi*16 + kh*4 + reg, p);
    }
  }
}

// ---------------------------------------------------------------------------
// Builders (wave-per-row, vectorized, write pads)
__global__ __launch_bounds__(256) void k_build_Aq(const unsigned short* __restrict__ hb,
    const float* __restrict__ tv, const int* __restrict__ q_rows,
    unsigned short* __restrict__ Aq, int nq){
  int w = blockIdx.x*4 + (threadIdx.x>>6), lane = threadIdx.x & 63;
  int nw = gridDim.x*4;
  for (int i = w; i < nq; i += nw){
    int row = q_rows[i]; int b = row & (B_-1);
    unsigned short* dst = Aq + (size_t)i*512;
    if (row < B_){
      for (int j2 = lane; j2 < 225; j2 += 64) ((unsigned int*)dst)[j2] = 0u;
    } else {
      const unsigned int* src = (const unsigned int*)(hb + (size_t)(row-B_)*H_);
      for (int j2 = lane; j2 < 225; j2 += 64) ((unsigned int*)dst)[j2] = src[j2];
    }
    int k = 450 + lane;
    if (k < 512){
      unsigned short v = 0;
      if (k < 506) v = f2b(tv[b*L_ + (k-450)]);
      dst[k] = v;
    }
  }
}

__global__ __launch_bounds__(256) void k_build_Ap(const unsigned short* __restrict__ hb,
    const unsigned short* __restrict__ xb, const float* __restrict__ tv,
    const int* __restrict__ root_ids, const int* __restrict__ step_v,
    unsigned short* __restrict__ Ap){
  int w = blockIdx.x*4 + (threadIdx.x>>6), lane = threadIdx.x & 63;
  int nw = gridDim.x*4;
  for (int i = w; i < NPROWS; i += nw){
    int b = i & (B_-1);
    unsigned short* dst = Ap + (size_t)i*960;
    int xn = (i < B_) ? root_ids[b] : step_v[i - B_];
    const unsigned int* xr = (const unsigned int*)(xb + (size_t)xn*KS);
    for (int j2 = lane; j2 < 225; j2 += 64) ((unsigned int*)dst)[j2] = xr[j2];
    if (i < B_){
      for (int j2 = lane; j2 < 225; j2 += 64) ((unsigned int*)(dst + 450))[j2] = 0u;
    } else {
      const unsigned int* hr = (const unsigned int*)(hb + (size_t)(i-B_)*H_);
      for (int j2 = lane; j2 < 225; j2 += 64) ((unsigned int*)(dst + 450))[j2] = hr[j2];
    }
    int k = 900 + lane;
    if (k < 960){
      unsigned short v = 0;
      if (k < 956) v = f2b(tv[b*L_ + (k-900)]);
      dst[k] = v;
    }
  }
}

// ---------------------------------------------------------------------------
// q reduce: wave-per-row, register-cached row, shuffle reductions
__global__ __launch_bounds__(256) void k_qreduce2(const float* __restrict__ logits,
    const int* __restrict__ q_tgt, int nq, float* __restrict__ out){
  int w = blockIdx.x*4 + (threadIdx.x>>6), lane = threadIdx.x & 63;
  int nw = gridDim.x*4;
  float qloss = 0.f, qacc = 0.f;
  for (int i = w; i < nq; i += nw){
    const float4* lr4 = (const float4*)(logits + (size_t)i*V_);
    float4 vals[4]; int cnt = 0;
    float mx = -INFINITY; int mi = 0x7fffffff;
    for (int j4 = lane; j4 < 195; j4 += 64){
      float4 v = lr4[j4]; vals[cnt++] = v;
      #pragma unroll
      for (int u = 0; u < 4; ++u){
        float f = ((float*)&v)[u];
        if (f > mx){ mx = f; mi = j4*4 + u; }
      }
    }
    #pragma unroll
    for (int off = 32; off; off >>= 1){
      float omx = __shfl_xor(mx, off); int omi = __shfl_xor(mi, off);
      if (omx > mx || (omx == mx && omi < mi)){ mx = omx; mi = omi; }
    }
    float ps = 0.f; cnt = 0;
    for (int j4 = lane; j4 < 195; j4 += 64){
      float4 v = vals[cnt++];
      ps += expf(v.x-mx) + expf(v.y-mx) + expf(v.z-mx) + expf(v.w-mx);
    }
    #pragma unroll
    for (int off = 32; off; off >>= 1) ps += __shfl_xor(ps, off);
    if (lane == 0){
      int tg = q_tgt[i];
      float lt = logits[(size_t)i*V_ + tg];
      qloss += mx + logf(ps) - lt;
      qacc  += (mi == tg) ? 1.f : 0.f;
    }
  }
  if (lane == 0){
    atomicAdd(out+0, qloss*(1.0f/B_));
    atomicAdd(out+2, qacc *(1.0f/(float)nq));
  }
}

// p final: BCE + acc from plog
__global__ __launch_bounds__(256) void k_pfinal(const float* __restrict__ plog,
    const float* __restrict__ bs, const int* __restrict__ p_tgt, float* __restrict__ out){
  int i = blockIdx.x*256 + threadIdx.x;
  float loss = 0.f, acc = 0.f;
  if (i < NPROWS){
    float pl = plog[i] + bs[0];
    float tgt = (float)p_tgt[i];
    loss = fmaxf(pl, 0.f) + log1pf(expf(-fabsf(pl))) - pl*tgt;
    acc = (((pl > 0.f) ? 1 : 0) == p_tgt[i]) ? 1.f : 0.f;
  }
  #pragma unroll
  for (int off = 32; off; off >>= 1){
    loss += __shfl_xor(loss, off); acc += __shfl_xor(acc, off);
  }
  if ((threadIdx.x & 63) == 0){
    atomicAdd(out+1, loss*(1.0f/B_));
    atomicAdd(out+3, acc *(1.0f/(float)NPROWS));
  }
}

// ---------------------------------------------------------------------------
extern "C" void kernel_launch(void* const* d_in, const int* in_sizes, int n_in,
                              void* d_out, int out_size, void* d_ws, size_t ws_size,
                              hipStream_t stream){
  const float* tree_vec = (const float*)d_in[0];
  const float* emb  = (const float*)d_in[1];
  const float* Wz   = (const float*)d_in[2];
  const float* bz   = (const float*)d_in[3];
  const float* Wh   = (const float*)d_in[4];
  const float* bh   = (const float*)d_in[5];
  const float* Wr   = (const float*)d_in[6];
  const float* Ur   = (const float*)d_in[7];
  const float* br   = (const float*)d_in[8];
  const float* Ww   = (const float*)d_in[9];
  const float* bw   = (const float*)d_in[10];
  const float* Uw   = (const float*)d_in[11];
  const float* bu   = (const float*)d_in[12];
  const float* Wo   = (const float*)d_in[13];
  const float* bo   = (const float*)d_in[14];
  const float* Us   = (const float*)d_in[15];
  const float* bs   = (const float*)d_in[16];
  const int* wid      = (const int*)d_in[17];
  const int* root_ids = (const int*)d_in[18];
  const int* edge_src = (const int*)d_in[19];
  const int* edge_dst = (const int*)d_in[20];
  const int* edge_pred= (const int*)d_in[21];
  const int* node_in  = (const int*)d_in[22];
  const int* step_eid = (const int*)d_in[23];
  const int* step_v   = (const int*)d_in[24];
  const int* q_rows   = (const int*)d_in[25];
  const int* q_tgt    = (const int*)d_in[26];
  const int* p_tgt    = (const int*)d_in[27];
  int P  = in_sizes[21] / NEDGES;  if (P > MAXP) P = MAXP;
  int Dn = in_sizes[22] / NNODES;  if (Dn > MAXD) Dn = MAXD;
  int nq = in_sizes[25];           // 10240

  char* ws = (char*)d_ws;
  // --- layout ---
  const size_t XB_OFF  = 0;                         // bf16 [10240][480] = 9,830,400
  const size_t HB_OFF  = 9830400;                   // bf16 [19456][450] = 17,510,400
  const size_t M_OFF   = 27340800;                  // bf16 [19457][480] = 18,678,720 (pad 18,678,784)
  const size_t RM_OFF  = M_OFF + 18678784;          // = 46,019,584
  const size_t WZB_OFF = RM_OFF + 18678784;         // = 64,698,368  bf16 [512][480]
  const size_t WHB_OFF = WZB_OFF + 491520;
  const size_t URT_OFF = WHB_OFF + 491520;
  const size_t WZTOP_OFF = URT_OFF + 491520;        // = 66,172,928
  const size_t WHTOP_OFF = WZTOP_OFF + 491520;
  const size_t WRT_OFF   = WHTOP_OFF + 491520;
  const size_t WWT_OFF = WRT_OFF + 491520;          // = 67,647,488  bf16 [512][512]
  const size_t UWT_OFF = WWT_OFF + 524288;          // bf16 [512][960]
  const size_t WOT_OFF = UWT_OFF + 983040;          // bf16 [832][512]
  const size_t XWZ_OFF = WOT_OFF + 851968;          // = 70,006,784  bf16 [10240][450]
  const size_t XWH_OFF = XWZ_OFF + 9216000;
  const size_t XWR_OFF = XWH_OFF + 9216000;         // ends 97,654,784
  // overlays after scan:
  const size_t LQ_OFF  = M_OFF;                     // f32 [10240][780] = 31,948,800 (fits M+RM)
  const size_t AQ_OFF  = XWZ_OFF;                   // bf16 [10240][512] (XW dead post-scan)
  const size_t HQB_OFF = AQ_OFF + 10485760;
  const size_t PL_OFF  = HQB_OFF + 10485760;        // f32 [19968]
  const size_t AP_OFF  = M_OFF;                     // bf16 [19968][960] = 38,338,560 (covers M..scan-weights, all dead)

  unsigned short* xb = (unsigned short*)(ws + XB_OFF);
  unsigned short* hb = (unsigned short*)(ws + HB_OFF);
  unsigned short* m_ = (unsigned short*)(ws + M_OFF);
  unsigned short* rm = (unsigned short*)(ws + RM_OFF);
  unsigned short* WzB = (unsigned short*)(ws + WZB_OFF);
  unsigned short* WhB = (unsigned short*)(ws + WHB_OFF);
  unsigned short* UrT = (unsigned short*)(ws + URT_OFF);
  unsigned short* WzTop = (unsigned short*)(ws + WZTOP_OFF);
  unsigned short* WhTop = (unsigned short*)(ws + WHTOP_OFF);
  unsigned short* WrT = (unsigned short*)(ws + WRT_OFF);
  unsigned short* WwT = (unsigned short*)(ws + WWT_OFF);
  unsigned short* UwT = (unsigned short*)(ws + UWT_OFF);
  unsigned short* WoT = (unsigned short*)(ws + WOT_OFF);
  unsigned short* XWz = (unsigned short*)(ws + XWZ_OFF);
  unsigned short* XWh = (unsigned short*)(ws + XWH_OFF);
  unsigned short* XWr = (unsigned short*)(ws + XWR_OFF);

  hipMemsetAsync(ws + M_OFF, 0, 2*18678784ull, stream);   // m, rm (incl sentinel+pads)
  hipMemsetAsync(d_out, 0, (size_t)out_size*sizeof(float), stream);

  k_gather_xb<<<2560, 256, 0, stream>>>(emb, wid, xb);

  // scan weights: bottom halves (K rows 450..899) + Ur; top halves for XW precompute
  k_wt<<<512, 256, 0, stream>>>(Wz + 450*450, Wz, 450, 450, 450, WzB, KS);
  k_wt<<<512, 256, 0, stream>>>(Wh + 450*450, Wh, 450, 450, 450, WhB, KS);
  k_wt<<<512, 256, 0, stream>>>(Ur, Ur, 450, 450, 450, UrT, KS);
  k_wt<<<512, 256, 0, stream>>>(Wz, Wz, 450, 450, 450, WzTop, KS);
  k_wt<<<512, 256, 0, stream>>>(Wh, Wh, 450, 450, 450, WhTop, KS);
  k_wt<<<512, 256, 0, stream>>>(Wr, Wr, 450, 450, 450, WrT, KS);
  k_wt<<<512, 256, 0, stream>>>(Ww, Ww, 506, 506, 450, WwT, 512);
  k_wt<<<512, 256, 0, stream>>>(Uw, Uw, 956, 956, 450, UwT, 960);
  k_wt<<<832, 256, 0, stream>>>(Wo, Wo, 450, 450, 780, WoT, 512);

  // XW precompute (bias folded): XWz = xb@WzTop + bz, etc.  [10240][450] bf16
  k_head_mfma<<<dim3(8,160), 256, 0, stream>>>(xb, WzTop, KS, bz, H_, 0, nullptr, 0, XWz, H_);
  k_head_mfma<<<dim3(8,160), 256, 0, stream>>>(xb, WhTop, KS, bh, H_, 0, nullptr, 0, XWh, H_);
  k_head_mfma<<<dim3(8,160), 256, 0, stream>>>(xb, WrT,   KS, br, H_, 0, nullptr, 0, XWr, H_);

  // ---- cooperative fused scan ----
  ScanP sp;
  sp.WzB = WzB; sp.WhB = WhB; sp.UrT = UrT;
  sp.XWz = XWz; sp.XWh = XWh; sp.XWr = XWr;
  sp.edge_src = edge_src; sp.edge_dst = edge_dst; sp.edge_pred = edge_pred;
  sp.node_in = node_in; sp.step_eid = step_eid; sp.step_v = step_v;
  sp.m = m_; sp.rm = rm; sp.hb = hb;
  sp.P = P; sp.Dn = Dn;
  void* kargs[] = { &sp };
  hipLaunchCooperativeKernel(k_scan_coop, dim3(64), dim3(1024), kargs, 0, stream);

  // ---- q head ----
  unsigned short* Aq  = (unsigned short*)(ws + AQ_OFF);
  float* logitsq      = (float*)(ws + LQ_OFF);
  unsigned short* hqb = (unsigned short*)(ws + HQB_OFF);
  float* plog         = (float*)(ws + PL_OFF);
  hipMemsetAsync(plog, 0, (size_t)NPROWS*4, stream);

  k_build_Aq<<<640, 256, 0, stream>>>(hb, tree_vec, q_rows, Aq, nq);
  k_head_mfma<<<dim3(8, nq/64), 256, 0, stream>>>(Aq, WwT, 512, bw, H_, 1,
      nullptr, 0, hqb, 512);
  k_head_mfma<<<dim3(13, nq/64), 256, 0, stream>>>(hqb, WoT, 512, bo, V_, 0,
      logitsq, V_, nullptr, 0);
  k_qreduce2<<<320, 256, 0, stream>>>(logitsq, q_tgt, nq, (float*)d_out);

  // ---- p head ----
  unsigned short* Ap = (unsigned short*)(ws + AP_OFF);
  k_build_Ap<<<1248, 256, 0, stream>>>(hb, xb, tree_vec, root_ids, step_v, Ap);
  k_head_p<<<dim3(8, NPROWS/64), 256, 0, stream>>>(Ap, UwT, bu, Us, plog);
  k_pfinal<<<78, 256, 0, stream>>>(plog, bs, p_tgt, (float*)d_out);
}